// Round 9
// baseline (416.279 us; speedup 1.0000x reference)
//
#include <hip/hip_runtime.h>

#define D_MODEL 1024
#define NHEADS  16
#define DEPTH   64
#define BATCH   2
#define SEQ     2048
#define MROWS   (BATCH * SEQ)   // 4096
#define QSCALE  0.18033688f     // 0.125 * log2(e); folded into Q projection

typedef unsigned short u16;
typedef unsigned int   u32;
typedef unsigned long long u64;
typedef __bf16 bf16x8 __attribute__((ext_vector_type(8)));
typedef float  f32x4  __attribute__((ext_vector_type(4)));

__device__ __forceinline__ u16 f2b(float f) {
    return __builtin_bit_cast(u16, static_cast<__bf16>(f));   // v_cvt RNE
}
__device__ __forceinline__ bf16x8 ldb8(const u16* p) {
    return __builtin_bit_cast(bf16x8, *(const uint4*)p);
}

// ---------------------------------------------------------------------------
// Pack mask f32 [B,S,S] (1 => masked) into bit-words: word (b*S+q)*32 + k64.
// ---------------------------------------------------------------------------
__global__ __launch_bounds__(256) void pack_mask(
    const float* __restrict__ mask, u64* __restrict__ bits)
{
    const int w    = blockIdx.x * 4 + (threadIdx.x >> 6);
    const int lane = threadIdx.x & 63;
    float m = mask[(size_t)w * 64 + lane];
    u64 b = __ballot(m > 0.5f);
    if (lane == 0) bits[w] = b;
}

// ---------------------------------------------------------------------------
// One-time f32 -> bf16 conversion of q,k,v (4M elems each) and the four
// weight matrices (1M each). 8 elems/thread, 16B stores. Grid 8192.
// ---------------------------------------------------------------------------
__global__ __launch_bounds__(256) void cvt_all(
    const float* __restrict__ q,  const float* __restrict__ k,  const float* __restrict__ v,
    const float* __restrict__ wq, const float* __restrict__ wk, const float* __restrict__ wv,
    const float* __restrict__ wo,
    u16* __restrict__ qb, u16* __restrict__ kb, u16* __restrict__ vb,
    u16* __restrict__ wqb, u16* __restrict__ wkb, u16* __restrict__ wvb,
    u16* __restrict__ wob)
{
    const int blk = blockIdx.x;
    const float* src; u16* dst; size_t base;
    if (blk < 6144) {
        int t = blk >> 11;
        src = (t == 0) ? q : (t == 1) ? k : v;
        dst = (t == 0) ? qb : (t == 1) ? kb : vb;
        base = (size_t)(blk & 2047) * 2048;
    } else {
        int t = (blk - 6144) >> 9;
        src = (t == 0) ? wq : (t == 1) ? wk : (t == 2) ? wv : wo;
        dst = (t == 0) ? wqb : (t == 1) ? wkb : (t == 2) ? wvb : wob;
        base = (size_t)((blk - 6144) & 511) * 2048;
    }
    size_t e = base + (size_t)threadIdx.x * 8;
    float4 f0 = *(const float4*)&src[e];
    float4 f1 = *(const float4*)&src[e + 4];
    union { ushort s[8]; uint4 u; } o;
    o.s[0] = f2b(f0.x); o.s[1] = f2b(f0.y); o.s[2] = f2b(f0.z); o.s[3] = f2b(f0.w);
    o.s[4] = f2b(f1.x); o.s[5] = f2b(f1.y); o.s[6] = f2b(f1.z); o.s[7] = f2b(f1.w);
    *(uint4*)&dst[e] = o.u;
}

// ---------------------------------------------------------------------------
// Q/K/V projection, bf16 operands (tier A). BM=128 BN=128 BK=32, dbuf
// register prefetch. z==0 output pre-scaled by QSCALE. Grid (8,32,3).
// ---------------------------------------------------------------------------
__global__ __launch_bounds__(256, 3) void proj3_b(
    const u16* __restrict__ xq, const u16* __restrict__ xk, const u16* __restrict__ xv,
    const u16* __restrict__ wq, const u16* __restrict__ wk, const u16* __restrict__ wv,
    const float* __restrict__ bq, const float* __restrict__ bk, const float* __restrict__ bv,
    u16* __restrict__ qws, u16* __restrict__ kws, u16* __restrict__ vtws)
{
    __shared__ __align__(16) u16 ldsA[128 * 40];
    __shared__ __align__(16) u16 ldsB[128 * 40];

    const int z = blockIdx.z;
    const u16* X    = (z == 0) ? xq : (z == 1) ? xk : xv;
    const u16* W    = (z == 0) ? wq : (z == 1) ? wk : wv;
    const float* Bi = (z == 0) ? bq : (z == 1) ? bk : bv;
    u16* dst        = (z == 0) ? qws : (z == 1) ? kws : vtws;

    const int tid  = threadIdx.x;
    const int wv_  = tid >> 6;
    const int lane = tid & 63;
    const int quad = lane >> 4;
    const int l15  = lane & 15;
    const int bx = blockIdx.x, by = blockIdx.y;
    const int wm = (wv_ >> 1) * 64;
    const int wn = (wv_ & 1) * 64;

    f32x4 acc[4][4];
    for (int i = 0; i < 4; ++i)
        for (int j = 0; j < 4; ++j)
            acc[i][j] = (f32x4){0.f, 0.f, 0.f, 0.f};

    const int rowA0 = by * 128;
    const int rowB0 = bx * 128;

    // staging: row = (tid>>2) + i*64, col8 = (tid&3)*8  (16B per thread-chunk)
    const int sr = tid >> 2;
    const int sc = (tid & 3) * 8;

    uint4 pA[2], pB[2];
    #pragma unroll
    for (int i = 0; i < 2; ++i) {
        pA[i] = *(const uint4*)&X[(size_t)(rowA0 + sr + i * 64) * D_MODEL + sc];
        pB[i] = *(const uint4*)&W[(size_t)(rowB0 + sr + i * 64) * D_MODEL + sc];
    }

    for (int it = 0; it < 32; ++it) {
        #pragma unroll
        for (int i = 0; i < 2; ++i) {
            *(uint4*)&ldsA[(sr + i * 64) * 40 + sc] = pA[i];
            *(uint4*)&ldsB[(sr + i * 64) * 40 + sc] = pB[i];
        }
        __syncthreads();

        if (it < 31) {
            const int k0 = (it + 1) * 32;
            #pragma unroll
            for (int i = 0; i < 2; ++i) {
                pA[i] = *(const uint4*)&X[(size_t)(rowA0 + sr + i * 64) * D_MODEL + k0 + sc];
                pB[i] = *(const uint4*)&W[(size_t)(rowB0 + sr + i * 64) * D_MODEL + k0 + sc];
            }
        }

        bf16x8 af[4], bfr[4];
        #pragma unroll
        for (int t = 0; t < 4; ++t) {
            af[t]  = ldb8(&ldsA[(wm + t * 16 + l15) * 40 + quad * 8]);
            bfr[t] = ldb8(&ldsB[(wn + t * 16 + l15) * 40 + quad * 8]);
        }
        #pragma unroll
        for (int mt = 0; mt < 4; ++mt)
            #pragma unroll
            for (int nt = 0; nt < 4; ++nt)
                acc[mt][nt] = __builtin_amdgcn_mfma_f32_16x16x32_bf16(af[mt], bfr[nt], acc[mt][nt], 0, 0, 0);
        __syncthreads();
    }

    #pragma unroll
    for (int nt = 0; nt < 4; ++nt) {
        int n = bx * 128 + wn + nt * 16 + l15;
        float bvv = Bi[n];
        int h = n >> 6, d = n & 63;
        #pragma unroll
        for (int mt = 0; mt < 4; ++mt) {
            #pragma unroll
            for (int r = 0; r < 4; ++r) {
                int m = by * 128 + wm + mt * 16 + quad * 4 + r;
                float c = acc[mt][nt][r] + bvv;
                if (z == 0) c *= QSCALE;
                int b = m >> 11, s = m & (SEQ - 1);
                if (z != 2)
                    dst[(((size_t)(b * NHEADS + h) * SEQ) + s) * DEPTH + d] = f2b(c);
                else
                    dst[(((size_t)(b * NHEADS + h) * DEPTH) + d) * SEQ + s] = f2b(c);
            }
        }
    }
}

// ---------------------------------------------------------------------------
// Q/K/V projection, f32 operands (tier B fallback = round-8 path + QSCALE).
// ---------------------------------------------------------------------------
__global__ __launch_bounds__(256, 3) void proj3_f(
    const float* __restrict__ q, const float* __restrict__ k, const float* __restrict__ v,
    const float* __restrict__ wq, const float* __restrict__ wk, const float* __restrict__ wv,
    const float* __restrict__ bq, const float* __restrict__ bk, const float* __restrict__ bv,
    u16* __restrict__ qws, u16* __restrict__ kws, u16* __restrict__ vtws)
{
    __shared__ __align__(16) u16 ldsA[128 * 40];
    __shared__ __align__(16) u16 ldsB[128 * 40];

    const int z = blockIdx.z;
    const float* X  = (z == 0) ? q  : (z == 1) ? k  : v;
    const float* W  = (z == 0) ? wq : (z == 1) ? wk : wv;
    const float* Bi = (z == 0) ? bq : (z == 1) ? bk : bv;
    u16* dst        = (z == 0) ? qws : (z == 1) ? kws : vtws;

    const int tid  = threadIdx.x;
    const int wv_  = tid >> 6;
    const int lane = tid & 63;
    const int quad = lane >> 4;
    const int l15  = lane & 15;
    const int bx = blockIdx.x, by = blockIdx.y;
    const int wm = (wv_ >> 1) * 64;
    const int wn = (wv_ & 1) * 64;

    f32x4 acc[4][4];
    for (int i = 0; i < 4; ++i)
        for (int j = 0; j < 4; ++j)
            acc[i][j] = (f32x4){0.f, 0.f, 0.f, 0.f};

    const int rowA0 = by * 128;
    const int rowB0 = bx * 128;

    const int sr = tid >> 3;
    const int sc = (tid & 7) * 4;

    float4 pa[4], pb[4];
    #pragma unroll
    for (int i = 0; i < 4; ++i) {
        pa[i] = *(const float4*)&X[(size_t)(rowA0 + sr + i * 32) * D_MODEL + sc];
        pb[i] = *(const float4*)&W[(size_t)(rowB0 + sr + i * 32) * D_MODEL + sc];
    }

    for (int it = 0; it < 32; ++it) {
        #pragma unroll
        for (int i = 0; i < 4; ++i) {
            ushort4 ha, hb;
            ha.x = f2b(pa[i].x); ha.y = f2b(pa[i].y); ha.z = f2b(pa[i].z); ha.w = f2b(pa[i].w);
            hb.x = f2b(pb[i].x); hb.y = f2b(pb[i].y); hb.z = f2b(pb[i].z); hb.w = f2b(pb[i].w);
            *(ushort4*)&ldsA[(sr + i * 32) * 40 + sc] = ha;
            *(ushort4*)&ldsB[(sr + i * 32) * 40 + sc] = hb;
        }
        __syncthreads();

        if (it < 31) {
            const int k0 = (it + 1) * 32;
            #pragma unroll
            for (int i = 0; i < 4; ++i) {
                pa[i] = *(const float4*)&X[(size_t)(rowA0 + sr + i * 32) * D_MODEL + k0 + sc];
                pb[i] = *(const float4*)&W[(size_t)(rowB0 + sr + i * 32) * D_MODEL + k0 + sc];
            }
        }

        bf16x8 af[4], bfr[4];
        #pragma unroll
        for (int t = 0; t < 4; ++t) {
            af[t]  = ldb8(&ldsA[(wm + t * 16 + l15) * 40 + quad * 8]);
            bfr[t] = ldb8(&ldsB[(wn + t * 16 + l15) * 40 + quad * 8]);
        }
        #pragma unroll
        for (int mt = 0; mt < 4; ++mt)
            #pragma unroll
            for (int nt = 0; nt < 4; ++nt)
                acc[mt][nt] = __builtin_amdgcn_mfma_f32_16x16x32_bf16(af[mt], bfr[nt], acc[mt][nt], 0, 0, 0);
        __syncthreads();
    }

    #pragma unroll
    for (int nt = 0; nt < 4; ++nt) {
        int n = bx * 128 + wn + nt * 16 + l15;
        float bvv = Bi[n];
        int h = n >> 6, d = n & 63;
        #pragma unroll
        for (int mt = 0; mt < 4; ++mt) {
            #pragma unroll
            for (int r = 0; r < 4; ++r) {
                int m = by * 128 + wm + mt * 16 + quad * 4 + r;
                float c = acc[mt][nt][r] + bvv;
                if (z == 0) c *= QSCALE;
                int b = m >> 11, s = m & (SEQ - 1);
                if (z != 2)
                    dst[(((size_t)(b * NHEADS + h) * SEQ) + s) * DEPTH + d] = f2b(c);
                else
                    dst[(((size_t)(b * NHEADS + h) * DEPTH) + d) * SEQ + s] = f2b(c);
            }
        }
    }
}

// ---------------------------------------------------------------------------
// Output projection. W_BF16: wob bf16 (tier A) else f32 (tier B).
// BM=128 BN=64 dbuf. Grid (16,32).
// ---------------------------------------------------------------------------
template <bool W_BF16>
__global__ __launch_bounds__(256) void gemm_out_t(
    const u16* __restrict__ X, const void* __restrict__ Wv,
    const float* __restrict__ bias, float* __restrict__ out)
{
    __shared__ __align__(16) u16 ldsA[128 * 40];
    __shared__ __align__(16) u16 ldsB[64 * 40];

    const int tid  = threadIdx.x;
    const int wv_  = tid >> 6;
    const int lane = tid & 63;
    const int quad = lane >> 4;
    const int l15  = lane & 15;
    const int bx = blockIdx.x, by = blockIdx.y;
    const int wm = (wv_ >> 1) * 64;
    const int wn = (wv_ & 1) * 32;

    f32x4 acc[4][2];
    for (int i = 0; i < 4; ++i)
        for (int j = 0; j < 2; ++j)
            acc[i][j] = (f32x4){0.f, 0.f, 0.f, 0.f};

    const int rowA0 = by * 128;
    const int rowB0 = bx * 64;

    const int ar = tid >> 2, akc = (tid & 3) * 8;
    const int br = tid >> 3, bc = (tid & 7) * 4;   // f32 path
    const int ubr = tid >> 2, ubc = (tid & 3) * 8; // bf16 path (64 rows x 32)

    uint4  paA[2];
    float4 paBf[2];
    uint4  paBb;
    #pragma unroll
    for (int i = 0; i < 2; ++i)
        paA[i] = *(const uint4*)&X[(size_t)(rowA0 + ar + i * 64) * D_MODEL + akc];
    if (W_BF16) {
        paBb = *(const uint4*)&((const u16*)Wv)[(size_t)(rowB0 + ubr) * D_MODEL + ubc];
    } else {
        #pragma unroll
        for (int i = 0; i < 2; ++i)
            paBf[i] = *(const float4*)&((const float*)Wv)[(size_t)(rowB0 + br + i * 32) * D_MODEL + bc];
    }

    for (int it = 0; it < 32; ++it) {
        #pragma unroll
        for (int i = 0; i < 2; ++i)
            *(uint4*)&ldsA[(ar + i * 64) * 40 + akc] = paA[i];
        if (W_BF16) {
            *(uint4*)&ldsB[ubr * 40 + ubc] = paBb;
        } else {
            #pragma unroll
            for (int i = 0; i < 2; ++i) {
                ushort4 hb;
                hb.x = f2b(paBf[i].x); hb.y = f2b(paBf[i].y);
                hb.z = f2b(paBf[i].z); hb.w = f2b(paBf[i].w);
                *(ushort4*)&ldsB[(br + i * 32) * 40 + bc] = hb;
            }
        }
        __syncthreads();

        if (it < 31) {
            const int k0 = (it + 1) * 32;
            #pragma unroll
            for (int i = 0; i < 2; ++i)
                paA[i] = *(const uint4*)&X[(size_t)(rowA0 + ar + i * 64) * D_MODEL + k0 + akc];
            if (W_BF16) {
                paBb = *(const uint4*)&((const u16*)Wv)[(size_t)(rowB0 + ubr) * D_MODEL + k0 + ubc];
            } else {
                #pragma unroll
                for (int i = 0; i < 2; ++i)
                    paBf[i] = *(const float4*)&((const float*)Wv)[(size_t)(rowB0 + br + i * 32) * D_MODEL + k0 + bc];
            }
        }

        bf16x8 af[4], bfr[2];
        #pragma unroll
        for (int t = 0; t < 4; ++t)
            af[t] = ldb8(&ldsA[(wm + t * 16 + l15) * 40 + quad * 8]);
        #pragma unroll
        for (int t = 0; t < 2; ++t)
            bfr[t] = ldb8(&ldsB[(wn + t * 16 + l15) * 40 + quad * 8]);
        #pragma unroll
        for (int mt = 0; mt < 4; ++mt)
            #pragma unroll
            for (int nt = 0; nt < 2; ++nt)
                acc[mt][nt] = __builtin_amdgcn_mfma_f32_16x16x32_bf16(af[mt], bfr[nt], acc[mt][nt], 0, 0, 0);
        __syncthreads();
    }

    #pragma unroll
    for (int nt = 0; nt < 2; ++nt) {
        int n = bx * 64 + wn + nt * 16 + l15;
        float bvv = bias[n];
        #pragma unroll
        for (int mt = 0; mt < 4; ++mt) {
            #pragma unroll
            for (int r = 0; r < 4; ++r) {
                int m = by * 128 + wm + mt * 16 + quad * 4 + r;
                out[(size_t)m * D_MODEL + n] = acc[mt][nt][r] + bvv;
            }
        }
    }
}

// ---------------------------------------------------------------------------
// Flash attention v3: Q pre-scaled (exp2 direct), cheap mask-bit extraction.
// Structure (LDS-staged dbuf K/V, packed mask) unchanged from round 8.
// ---------------------------------------------------------------------------
__global__ __launch_bounds__(256, 3) void flash_attn(
    const u16* __restrict__ Q, const u16* __restrict__ K,
    const u16* __restrict__ Vt, const u64* __restrict__ maskbits,
    u16* __restrict__ O)
{
    __shared__ __align__(16) u16 ldsK[2][64 * 64];
    __shared__ __align__(16) u16 ldsV[2][64 * 64];
    __shared__ __align__(16) u16 ldsP[4][16 * 72];

    const int tid  = threadIdx.x;
    const int wv_  = tid >> 6;
    const int lane = tid & 63;
    const int quad = lane >> 4;
    const int l15  = lane & 15;
    const int bh = blockIdx.y;
    const int b  = bh >> 4, h = bh & 15;
    const int q0 = blockIdx.x * 64 + wv_ * 16;

    const u16* Qb = Q  + (size_t)bh * SEQ * DEPTH;
    const u16* Kb = K  + (size_t)bh * SEQ * DEPTH;
    const u16* Vb = Vt + (size_t)bh * DEPTH * SEQ;
    const u64* MB = maskbits + (size_t)b * SEQ * (SEQ / 64);

    const int srow = tid >> 3;
    const int sc8  = tid & 7;
    const int swz  = ((sc8 ^ (srow & 7)) * 8);
    const int kdst0 = srow * 64 + swz;
    const int kdst1 = (srow + 32) * 64 + swz;

    const int xk0 = ((quad ^ (l15 & 7)) * 8);
    const int xk1 = (((4 + quad) ^ (l15 & 7)) * 8);

    bf16x8 aq0 = ldb8(&Qb[(q0 + l15) * DEPTH + quad * 8]);
    bf16x8 aq1 = ldb8(&Qb[(q0 + l15) * DEPTH + 32 + quad * 8]);

    f32x4 oa[4];
    for (int i = 0; i < 4; ++i) oa[i] = (f32x4){0.f, 0.f, 0.f, 0.f};
    float lrow[4] = {0.f, 0.f, 0.f, 0.f};

    u16* myP = ldsP[wv_];

    uint4 kreg0 = *(const uint4*)&Kb[(size_t)srow * DEPTH + sc8 * 8];
    uint4 kreg1 = *(const uint4*)&Kb[(size_t)(srow + 32) * DEPTH + sc8 * 8];
    uint4 vreg0 = *(const uint4*)&Vb[(size_t)srow * SEQ + sc8 * 8];
    uint4 vreg1 = *(const uint4*)&Vb[(size_t)(srow + 32) * SEQ + sc8 * 8];

    for (int it = 0; it < 32; ++it) {
        const int buf = it & 1;
        u16* Kl = ldsK[buf];
        u16* Vl = ldsV[buf];

        *(uint4*)&Kl[kdst0] = kreg0;
        *(uint4*)&Kl[kdst1] = kreg1;
        *(uint4*)&Vl[kdst0] = vreg0;
        *(uint4*)&Vl[kdst1] = vreg1;
        __syncthreads();

        if (it < 31) {
            const int kb2 = (it + 1) * 64;
            kreg0 = *(const uint4*)&Kb[(size_t)(kb2 + srow) * DEPTH + sc8 * 8];
            kreg1 = *(const uint4*)&Kb[(size_t)(kb2 + srow + 32) * DEPTH + sc8 * 8];
            vreg0 = *(const uint4*)&Vb[(size_t)srow * SEQ + kb2 + sc8 * 8];
            vreg1 = *(const uint4*)&Vb[(size_t)(srow + 32) * SEQ + kb2 + sc8 * 8];
        }

        // one 64-bit shift per q-row; constant-position bit tests per chunk
        u32 tlo[4], thi[4];
        #pragma unroll
        for (int r = 0; r < 4; ++r) {
            u64 t = MB[(size_t)(q0 + quad * 4 + r) * (SEQ / 64) + it] >> l15;
            tlo[r] = (u32)t;
            thi[r] = (u32)(t >> 32);
        }

        #pragma unroll
        for (int cc = 0; cc < 4; ++cc) {
            const int row = cc * 16 + l15;
            bf16x8 bk0 = ldb8(&Kl[row * 64 + xk0]);
            bf16x8 bk1 = ldb8(&Kl[row * 64 + xk1]);
            f32x4 z = (f32x4){0.f, 0.f, 0.f, 0.f};
            z = __builtin_amdgcn_mfma_f32_16x16x32_bf16(aq0, bk0, z, 0, 0, 0);
            z = __builtin_amdgcn_mfma_f32_16x16x32_bf16(aq1, bk1, z, 0, 0, 0);
            #pragma unroll
            for (int r = 0; r < 4; ++r) {
                u32 w   = (cc < 2) ? tlo[r] : thi[r];
                u32 bit = (cc & 1) ? ((w >> 16) & 1u) : (w & 1u);
                float e = exp2f(z[r]);           // Q pre-scaled by 0.125*log2(e)
                float p = bit ? 0.f : e;
                lrow[r] += p;
                myP[(quad * 4 + r) * 72 + cc * 16 + l15] = f2b(p);
            }
        }

        __builtin_amdgcn_wave_barrier();
        __builtin_amdgcn_s_waitcnt(0xc07f);   // lgkmcnt(0)
        __builtin_amdgcn_wave_barrier();
        bf16x8 pa0 = ldb8(&myP[l15 * 72 + quad * 8]);
        bf16x8 pa1 = ldb8(&myP[l15 * 72 + 32 + quad * 8]);

        #pragma unroll
        for (int n = 0; n < 4; ++n) {
            const int row = n * 16 + l15;
            bf16x8 bv0 = ldb8(&Vl[row * 64 + xk0]);
            bf16x8 bv1 = ldb8(&Vl[row * 64 + xk1]);
            oa[n] = __builtin_amdgcn_mfma_f32_16x16x32_bf16(pa0, bv0, oa[n], 0, 0, 0);
            oa[n] = __builtin_amdgcn_mfma_f32_16x16x32_bf16(pa1, bv1, oa[n], 0, 0, 0);
        }
    }

    #pragma unroll
    for (int r = 0; r < 4; ++r) {
        float s = lrow[r];
        #pragma unroll
        for (int off = 1; off < 16; off <<= 1)
            s += __shfl_xor(s, off, 64);
        lrow[r] = 1.0f / s;
    }
    #pragma unroll
    for (int n = 0; n < 4; ++n)
        #pragma unroll
        for (int r = 0; r < 4; ++r) {
            int m = q0 + quad * 4 + r;
            O[((size_t)b * SEQ + m) * D_MODEL + h * DEPTH + n * 16 + l15] =
                f2b(oa[n][r] * lrow[r]);
        }
}

// ---------------------------------------------------------------------------
extern "C" void kernel_launch(void* const* d_in, const int* in_sizes, int n_in,
                              void* d_out, int out_size, void* d_ws, size_t ws_size,
                              hipStream_t stream) {
    const float* q    = (const float*)d_in[0];
    const float* k    = (const float*)d_in[1];
    const float* v    = (const float*)d_in[2];
    const float* mask = (const float*)d_in[3];
    const float* wq   = (const float*)d_in[4];
    const float* bq   = (const float*)d_in[5];
    const float* wk   = (const float*)d_in[6];
    const float* bk   = (const float*)d_in[7];
    const float* wv   = (const float*)d_in[8];
    const float* bv   = (const float*)d_in[9];
    const float* wo   = (const float*)d_in[10];
    const float* bo   = (const float*)d_in[11];

    u16* base = (u16*)d_ws;
    const size_t seg = (size_t)BATCH * NHEADS * SEQ * DEPTH;  // 4M elems
    const size_t wseg = (size_t)D_MODEL * D_MODEL;            // 1M elems
    u16* qws  = base;
    u16* kws  = base + seg;
    u16* vtws = base + 2 * seg;
    u16* ows  = base + 3 * seg;

    // tier A needs: 4*seg + 3*seg (qb,kb,vb) + 4*wseg + 1MB mbits = 65 MB
    const size_t needA = (7 * seg + 4 * wseg) * 2 + (size_t)BATCH * SEQ * (SEQ / 64) * 8;
    const bool tierA = ws_size >= needA;

    dim3 blk(256);
    dim3 gp(D_MODEL / 128, MROWS / 128, 3);   // (8, 32, 3)
    dim3 ga(SEQ / 64, BATCH * NHEADS);        // (32, 32)
    dim3 go(D_MODEL / 64, MROWS / 128);       // (16, 32)

    if (tierA) {
        u16* qb  = base + 4 * seg;
        u16* kb  = base + 5 * seg;
        u16* vb  = base + 6 * seg;
        u16* wqb = base + 7 * seg;
        u16* wkb = wqb + wseg;
        u16* wvb = wkb + wseg;
        u16* wob = wvb + wseg;
        u64* mbits = (u64*)(wob + wseg);

        hipLaunchKernelGGL(cvt_all, dim3(8192), blk, 0, stream,
                           q, k, v, wq, wk, wv, wo, qb, kb, vb, wqb, wkb, wvb, wob);
        hipLaunchKernelGGL(pack_mask, dim3(BATCH * SEQ * (SEQ / 64) / 4), blk, 0, stream, mask, mbits);
        hipLaunchKernelGGL(proj3_b, gp, blk, 0, stream,
                           qb, kb, vb, wqb, wkb, wvb, bq, bk, bv, qws, kws, vtws);
        hipLaunchKernelGGL(flash_attn, ga, blk, 0, stream, qws, kws, vtws, mbits, ows);
        hipLaunchKernelGGL((gemm_out_t<true>), go, blk, 0, stream,
                           ows, (const void*)wob, bo, (float*)d_out);
    } else {
        u64* mbits = (u64*)(base + 4 * seg);
        hipLaunchKernelGGL(pack_mask, dim3(BATCH * SEQ * (SEQ / 64) / 4), blk, 0, stream, mask, mbits);
        hipLaunchKernelGGL(proj3_f, gp, blk, 0, stream,
                           q, k, v, wq, wk, wv, bq, bk, bv, qws, kws, vtws);
        hipLaunchKernelGGL(flash_attn, ga, blk, 0, stream, qws, kws, vtws, mbits, ows);
        hipLaunchKernelGGL((gemm_out_t<false>), go, blk, 0, stream,
                           ows, (const void*)wo, bo, (float*)d_out);
    }
}

// Round 10
// 348.083 us; speedup vs baseline: 1.1959x; 1.1959x over previous
//
#include <hip/hip_runtime.h>

#define D_MODEL 1024
#define NHEADS  16
#define DEPTH   64
#define BATCH   2
#define SEQ     2048
#define MROWS   (BATCH * SEQ)   // 4096
#define QSCALE  0.18033688f     // 0.125 * log2(e); folded into Q projection

typedef unsigned short u16;
typedef unsigned int   u32;
typedef unsigned long long u64;
typedef __bf16 bf16x8 __attribute__((ext_vector_type(8)));
typedef float  f32x4  __attribute__((ext_vector_type(4)));

__device__ __forceinline__ u16 f2b(float f) {
    return __builtin_bit_cast(u16, static_cast<__bf16>(f));   // v_cvt RNE
}
__device__ __forceinline__ bf16x8 ldb8(const u16* p) {
    return __builtin_bit_cast(bf16x8, *(const uint4*)p);
}

// ---------------------------------------------------------------------------
// Pack mask f32 [B,S,S] (1 => masked) into bit-words: word (b*S+q)*32 + k64.
// ---------------------------------------------------------------------------
__global__ __launch_bounds__(256) void pack_mask(
    const float* __restrict__ mask, u64* __restrict__ bits)
{
    const int w    = blockIdx.x * 4 + (threadIdx.x >> 6);
    const int lane = threadIdx.x & 63;
    float m = mask[(size_t)w * 64 + lane];
    u64 b = __ballot(m > 0.5f);
    if (lane == 0) bits[w] = b;
}

// ---------------------------------------------------------------------------
// Merged Q/K/V projection (round-8 structure): f32 operands, f32->bf16 fused
// into staging. BM=128 BN=128 BK=32, register-prefetch double-buffer.
// z==0 (Q) output pre-scaled by QSCALE. Grid (8,32,3) = 768 blocks.
// ---------------------------------------------------------------------------
__global__ __launch_bounds__(256, 3) void proj3(
    const float* __restrict__ q, const float* __restrict__ k, const float* __restrict__ v,
    const float* __restrict__ wq, const float* __restrict__ wk, const float* __restrict__ wv,
    const float* __restrict__ bq, const float* __restrict__ bk, const float* __restrict__ bv,
    u16* __restrict__ qws, u16* __restrict__ kws, u16* __restrict__ vtws)
{
    __shared__ __align__(16) u16 ldsA[128 * 40];
    __shared__ __align__(16) u16 ldsB[128 * 40];

    const int z = blockIdx.z;
    const float* X  = (z == 0) ? q  : (z == 1) ? k  : v;
    const float* W  = (z == 0) ? wq : (z == 1) ? wk : wv;
    const float* Bi = (z == 0) ? bq : (z == 1) ? bk : bv;
    u16* dst        = (z == 0) ? qws : (z == 1) ? kws : vtws;

    const int tid  = threadIdx.x;
    const int wv_  = tid >> 6;
    const int lane = tid & 63;
    const int quad = lane >> 4;
    const int l15  = lane & 15;
    const int bx = blockIdx.x, by = blockIdx.y;
    const int wm = (wv_ >> 1) * 64;
    const int wn = (wv_ & 1) * 64;

    f32x4 acc[4][4];
    for (int i = 0; i < 4; ++i)
        for (int j = 0; j < 4; ++j)
            acc[i][j] = (f32x4){0.f, 0.f, 0.f, 0.f};

    const int rowA0 = by * 128;
    const int rowB0 = bx * 128;

    const int sr = tid >> 3;
    const int sc = (tid & 7) * 4;

    float4 pa[4], pb[4];
    #pragma unroll
    for (int i = 0; i < 4; ++i) {
        pa[i] = *(const float4*)&X[(size_t)(rowA0 + sr + i * 32) * D_MODEL + sc];
        pb[i] = *(const float4*)&W[(size_t)(rowB0 + sr + i * 32) * D_MODEL + sc];
    }

    for (int it = 0; it < 32; ++it) {
        #pragma unroll
        for (int i = 0; i < 4; ++i) {
            ushort4 ha, hb;
            ha.x = f2b(pa[i].x); ha.y = f2b(pa[i].y); ha.z = f2b(pa[i].z); ha.w = f2b(pa[i].w);
            hb.x = f2b(pb[i].x); hb.y = f2b(pb[i].y); hb.z = f2b(pb[i].z); hb.w = f2b(pb[i].w);
            *(ushort4*)&ldsA[(sr + i * 32) * 40 + sc] = ha;
            *(ushort4*)&ldsB[(sr + i * 32) * 40 + sc] = hb;
        }
        __syncthreads();

        if (it < 31) {
            const int k0 = (it + 1) * 32;
            #pragma unroll
            for (int i = 0; i < 4; ++i) {
                pa[i] = *(const float4*)&X[(size_t)(rowA0 + sr + i * 32) * D_MODEL + k0 + sc];
                pb[i] = *(const float4*)&W[(size_t)(rowB0 + sr + i * 32) * D_MODEL + k0 + sc];
            }
        }

        bf16x8 af[4], bfr[4];
        #pragma unroll
        for (int t = 0; t < 4; ++t) {
            af[t]  = ldb8(&ldsA[(wm + t * 16 + l15) * 40 + quad * 8]);
            bfr[t] = ldb8(&ldsB[(wn + t * 16 + l15) * 40 + quad * 8]);
        }
        #pragma unroll
        for (int mt = 0; mt < 4; ++mt)
            #pragma unroll
            for (int nt = 0; nt < 4; ++nt)
                acc[mt][nt] = __builtin_amdgcn_mfma_f32_16x16x32_bf16(af[mt], bfr[nt], acc[mt][nt], 0, 0, 0);
        __syncthreads();
    }

    #pragma unroll
    for (int nt = 0; nt < 4; ++nt) {
        int n = bx * 128 + wn + nt * 16 + l15;
        float bvv = Bi[n];
        int h = n >> 6, d = n & 63;
        #pragma unroll
        for (int mt = 0; mt < 4; ++mt) {
            #pragma unroll
            for (int r = 0; r < 4; ++r) {
                int m = by * 128 + wm + mt * 16 + quad * 4 + r;
                float c = acc[mt][nt][r] + bvv;
                if (z == 0) c *= QSCALE;
                int b = m >> 11, s = m & (SEQ - 1);
                if (z != 2)
                    dst[(((size_t)(b * NHEADS + h) * SEQ) + s) * DEPTH + d] = f2b(c);
                else
                    dst[(((size_t)(b * NHEADS + h) * DEPTH) + d) * SEQ + s] = f2b(c);
            }
        }
    }
}

// ---------------------------------------------------------------------------
// Output projection (round-8 structure): O bf16 · Wo^T(f32, fused cvt) + bo.
// BM=128 BN=64 dbuf. Grid (16,32) = 512 blocks.
// ---------------------------------------------------------------------------
__global__ __launch_bounds__(256) void gemm_out(
    const u16* __restrict__ X, const float* __restrict__ W,
    const float* __restrict__ bias, float* __restrict__ out)
{
    __shared__ __align__(16) u16 ldsA[128 * 40];
    __shared__ __align__(16) u16 ldsB[64 * 40];

    const int tid  = threadIdx.x;
    const int wv_  = tid >> 6;
    const int lane = tid & 63;
    const int quad = lane >> 4;
    const int l15  = lane & 15;
    const int bx = blockIdx.x, by = blockIdx.y;
    const int wm = (wv_ >> 1) * 64;
    const int wn = (wv_ & 1) * 32;

    f32x4 acc[4][2];
    for (int i = 0; i < 4; ++i)
        for (int j = 0; j < 2; ++j)
            acc[i][j] = (f32x4){0.f, 0.f, 0.f, 0.f};

    const int rowA0 = by * 128;
    const int rowB0 = bx * 64;

    const int ar = tid >> 2, akc = (tid & 3) * 8;
    const int br = tid >> 3, bc = (tid & 7) * 4;

    uint4  paA[2];
    float4 paB[2];
    #pragma unroll
    for (int i = 0; i < 2; ++i) {
        paA[i] = *(const uint4*)&X[(size_t)(rowA0 + ar + i * 64) * D_MODEL + akc];
        paB[i] = *(const float4*)&W[(size_t)(rowB0 + br + i * 32) * D_MODEL + bc];
    }

    for (int it = 0; it < 32; ++it) {
        #pragma unroll
        for (int i = 0; i < 2; ++i) {
            *(uint4*)&ldsA[(ar + i * 64) * 40 + akc] = paA[i];
            ushort4 hb;
            hb.x = f2b(paB[i].x); hb.y = f2b(paB[i].y); hb.z = f2b(paB[i].z); hb.w = f2b(paB[i].w);
            *(ushort4*)&ldsB[(br + i * 32) * 40 + bc] = hb;
        }
        __syncthreads();

        if (it < 31) {
            const int k0 = (it + 1) * 32;
            #pragma unroll
            for (int i = 0; i < 2; ++i) {
                paA[i] = *(const uint4*)&X[(size_t)(rowA0 + ar + i * 64) * D_MODEL + k0 + akc];
                paB[i] = *(const float4*)&W[(size_t)(rowB0 + br + i * 32) * D_MODEL + k0 + bc];
            }
        }

        bf16x8 af[4], bfr[2];
        #pragma unroll
        for (int t = 0; t < 4; ++t)
            af[t] = ldb8(&ldsA[(wm + t * 16 + l15) * 40 + quad * 8]);
        #pragma unroll
        for (int t = 0; t < 2; ++t)
            bfr[t] = ldb8(&ldsB[(wn + t * 16 + l15) * 40 + quad * 8]);
        #pragma unroll
        for (int mt = 0; mt < 4; ++mt)
            #pragma unroll
            for (int nt = 0; nt < 2; ++nt)
                acc[mt][nt] = __builtin_amdgcn_mfma_f32_16x16x32_bf16(af[mt], bfr[nt], acc[mt][nt], 0, 0, 0);
        __syncthreads();
    }

    #pragma unroll
    for (int nt = 0; nt < 2; ++nt) {
        int n = bx * 64 + wn + nt * 16 + l15;
        float bvv = bias[n];
        #pragma unroll
        for (int mt = 0; mt < 4; ++mt) {
            #pragma unroll
            for (int r = 0; r < 4; ++r) {
                int m = by * 128 + wm + mt * 16 + quad * 4 + r;
                out[(size_t)m * D_MODEL + n] = acc[mt][nt][r] + bvv;
            }
        }
    }
}

// ---------------------------------------------------------------------------
// Flash attention v3: LDS-staged dbuf K/V, packed mask bits, Q pre-scaled
// (raw exp2), one 64-bit shift per q-row for mask extraction.
// Grid (S/64, B*H). Q,K: [B,H,S,64] bf16; Vt: [B,H,64,S] bf16.
// ---------------------------------------------------------------------------
__global__ __launch_bounds__(256, 3) void flash_attn(
    const u16* __restrict__ Q, const u16* __restrict__ K,
    const u16* __restrict__ Vt, const u64* __restrict__ maskbits,
    u16* __restrict__ O)
{
    __shared__ __align__(16) u16 ldsK[2][64 * 64];
    __shared__ __align__(16) u16 ldsV[2][64 * 64];
    __shared__ __align__(16) u16 ldsP[4][16 * 72];

    const int tid  = threadIdx.x;
    const int wv_  = tid >> 6;
    const int lane = tid & 63;
    const int quad = lane >> 4;
    const int l15  = lane & 15;
    const int bh = blockIdx.y;
    const int b  = bh >> 4, h = bh & 15;
    const int q0 = blockIdx.x * 64 + wv_ * 16;

    const u16* Qb = Q  + (size_t)bh * SEQ * DEPTH;
    const u16* Kb = K  + (size_t)bh * SEQ * DEPTH;
    const u16* Vb = Vt + (size_t)bh * DEPTH * SEQ;
    const u64* MB = maskbits + (size_t)b * SEQ * (SEQ / 64);

    const int srow = tid >> 3;
    const int sc8  = tid & 7;
    const int swz  = ((sc8 ^ (srow & 7)) * 8);
    const int kdst0 = srow * 64 + swz;
    const int kdst1 = (srow + 32) * 64 + swz;

    const int xk0 = ((quad ^ (l15 & 7)) * 8);
    const int xk1 = (((4 + quad) ^ (l15 & 7)) * 8);

    bf16x8 aq0 = ldb8(&Qb[(q0 + l15) * DEPTH + quad * 8]);
    bf16x8 aq1 = ldb8(&Qb[(q0 + l15) * DEPTH + 32 + quad * 8]);

    f32x4 oa[4];
    for (int i = 0; i < 4; ++i) oa[i] = (f32x4){0.f, 0.f, 0.f, 0.f};
    float lrow[4] = {0.f, 0.f, 0.f, 0.f};

    u16* myP = ldsP[wv_];

    uint4 kreg0 = *(const uint4*)&Kb[(size_t)srow * DEPTH + sc8 * 8];
    uint4 kreg1 = *(const uint4*)&Kb[(size_t)(srow + 32) * DEPTH + sc8 * 8];
    uint4 vreg0 = *(const uint4*)&Vb[(size_t)srow * SEQ + sc8 * 8];
    uint4 vreg1 = *(const uint4*)&Vb[(size_t)(srow + 32) * SEQ + sc8 * 8];

    for (int it = 0; it < 32; ++it) {
        const int buf = it & 1;
        u16* Kl = ldsK[buf];
        u16* Vl = ldsV[buf];

        *(uint4*)&Kl[kdst0] = kreg0;
        *(uint4*)&Kl[kdst1] = kreg1;
        *(uint4*)&Vl[kdst0] = vreg0;
        *(uint4*)&Vl[kdst1] = vreg1;
        __syncthreads();

        if (it < 31) {
            const int kb2 = (it + 1) * 64;
            kreg0 = *(const uint4*)&Kb[(size_t)(kb2 + srow) * DEPTH + sc8 * 8];
            kreg1 = *(const uint4*)&Kb[(size_t)(kb2 + srow + 32) * DEPTH + sc8 * 8];
            vreg0 = *(const uint4*)&Vb[(size_t)srow * SEQ + kb2 + sc8 * 8];
            vreg1 = *(const uint4*)&Vb[(size_t)(srow + 32) * SEQ + kb2 + sc8 * 8];
        }

        u32 tlo[4], thi[4];
        #pragma unroll
        for (int r = 0; r < 4; ++r) {
            u64 t = MB[(size_t)(q0 + quad * 4 + r) * (SEQ / 64) + it] >> l15;
            tlo[r] = (u32)t;
            thi[r] = (u32)(t >> 32);
        }

        #pragma unroll
        for (int cc = 0; cc < 4; ++cc) {
            const int row = cc * 16 + l15;
            bf16x8 bk0 = ldb8(&Kl[row * 64 + xk0]);
            bf16x8 bk1 = ldb8(&Kl[row * 64 + xk1]);
            f32x4 z = (f32x4){0.f, 0.f, 0.f, 0.f};
            z = __builtin_amdgcn_mfma_f32_16x16x32_bf16(aq0, bk0, z, 0, 0, 0);
            z = __builtin_amdgcn_mfma_f32_16x16x32_bf16(aq1, bk1, z, 0, 0, 0);
            #pragma unroll
            for (int r = 0; r < 4; ++r) {
                u32 w   = (cc < 2) ? tlo[r] : thi[r];
                u32 bit = (cc & 1) ? ((w >> 16) & 1u) : (w & 1u);
                float e = exp2f(z[r]);           // Q pre-scaled by 0.125*log2(e)
                float p = bit ? 0.f : e;
                lrow[r] += p;
                myP[(quad * 4 + r) * 72 + cc * 16 + l15] = f2b(p);
            }
        }

        __builtin_amdgcn_wave_barrier();
        __builtin_amdgcn_s_waitcnt(0xc07f);   // lgkmcnt(0)
        __builtin_amdgcn_wave_barrier();
        bf16x8 pa0 = ldb8(&myP[l15 * 72 + quad * 8]);
        bf16x8 pa1 = ldb8(&myP[l15 * 72 + 32 + quad * 8]);

        #pragma unroll
        for (int n = 0; n < 4; ++n) {
            const int row = n * 16 + l15;
            bf16x8 bv0 = ldb8(&Vl[row * 64 + xk0]);
            bf16x8 bv1 = ldb8(&Vl[row * 64 + xk1]);
            oa[n] = __builtin_amdgcn_mfma_f32_16x16x32_bf16(pa0, bv0, oa[n], 0, 0, 0);
            oa[n] = __builtin_amdgcn_mfma_f32_16x16x32_bf16(pa1, bv1, oa[n], 0, 0, 0);
        }
    }

    #pragma unroll
    for (int r = 0; r < 4; ++r) {
        float s = lrow[r];
        #pragma unroll
        for (int off = 1; off < 16; off <<= 1)
            s += __shfl_xor(s, off, 64);
        lrow[r] = 1.0f / s;
    }
    #pragma unroll
    for (int n = 0; n < 4; ++n)
        #pragma unroll
        for (int r = 0; r < 4; ++r) {
            int m = q0 + quad * 4 + r;
            O[((size_t)b * SEQ + m) * D_MODEL + h * DEPTH + n * 16 + l15] =
                f2b(oa[n][r] * lrow[r]);
        }
}

// ---------------------------------------------------------------------------
extern "C" void kernel_launch(void* const* d_in, const int* in_sizes, int n_in,
                              void* d_out, int out_size, void* d_ws, size_t ws_size,
                              hipStream_t stream) {
    const float* q    = (const float*)d_in[0];
    const float* k    = (const float*)d_in[1];
    const float* v    = (const float*)d_in[2];
    const float* mask = (const float*)d_in[3];
    const float* wq   = (const float*)d_in[4];
    const float* bq   = (const float*)d_in[5];
    const float* wk   = (const float*)d_in[6];
    const float* bk   = (const float*)d_in[7];
    const float* wv   = (const float*)d_in[8];
    const float* bv   = (const float*)d_in[9];
    const float* wo   = (const float*)d_in[10];
    const float* bo   = (const float*)d_in[11];

    // ws: [qws 8MB][kws 8MB][vtws 8MB][ows 8MB][maskbits 1MB]
    u16* base = (u16*)d_ws;
    const size_t seg = (size_t)BATCH * NHEADS * SEQ * DEPTH;  // 4M elems
    u16* qws  = base;
    u16* kws  = base + seg;
    u16* vtws = base + 2 * seg;
    u16* ows  = base + 3 * seg;
    u64* mbits = (u64*)(base + 4 * seg);

    dim3 blk(256);
    hipLaunchKernelGGL(pack_mask, dim3(BATCH * SEQ * (SEQ / 64) / 4), blk, 0, stream, mask, mbits);

    dim3 gp(D_MODEL / 128, MROWS / 128, 3);   // (8, 32, 3)
    hipLaunchKernelGGL(proj3, gp, blk, 0, stream,
                       q, k, v, wq, wk, wv, bq, bk, bv, qws, kws, vtws);

    dim3 ga(SEQ / 64, BATCH * NHEADS);        // (32, 32)
    hipLaunchKernelGGL(flash_attn, ga, blk, 0, stream, qws, kws, vtws, mbits, ows);

    dim3 go(D_MODEL / 64, MROWS / 128);       // (16, 32)
    hipLaunchKernelGGL(gemm_out, go, blk, 0, stream, ows, wo, bo, (float*)d_out);
}